// Round 11
// baseline (369.643 us; speedup 1.0000x reference)
//
#include <hip/hip_runtime.h>
#include <hip/hip_fp16.h>

// ---------------- Broadcast-10 fused constants ----------------
#define PARTS 10
#define NPP 20480                  // nodes per partition; 10*20480 = 204800 >= 200000
#define PADDED_N (PARTS * NPP)     // 204800
#define NXCD 8
#define GRP 6                      // chunk-groups per XCD
#define NCHUNKS (NXCD * GRP)       // 48 chunks; grid = 48*10 = 480 blocks (2/CU)
#define TPB_SCAN 1024

typedef int   vint4   __attribute__((ext_vector_type(4)));
typedef float vfloat4 __attribute__((ext_vector_type(4)));

// ---------------- Phase 0: W f32 -> f16 (2MB table => L2-resident gathers) ----------------
__global__ __launch_bounds__(256) void wconv_kernel(
    const float* __restrict__ W, __half* __restrict__ Wh, int n)
{
    int i4 = (blockIdx.x * 256 + threadIdx.x) * 4;
    if (i4 + 3 < n) {
        vfloat4 w = *reinterpret_cast<const vfloat4*>(W + i4);
        __half2 h01 = __floats2half2_rn(w.x, w.y);
        __half2 h23 = __floats2half2_rn(w.z, w.w);
        *reinterpret_cast<__half2*>(Wh + i4)     = h01;
        *reinterpret_cast<__half2*>(Wh + i4 + 2) = h23;
    } else {
        for (; i4 < n; ++i4) Wh[i4] = __float2half(W[i4]);
    }
}

// ---------------- Fused phase: gather + 10-partition broadcast scan ----------------
// Lessons baked in: XCD-aware mapping (r9: chunk readers share blockIdx%8 ->
// same XCD L2, FETCH 804->312); fp16 W (r10: gathers L2-hit, FETCH->89MB);
// r11: 80KB LDS -> 2 blocks/CU (32 waves) + manually batched loop for MLP
// (r10's VGPR=16 showed the compiler kept nothing in flight).
__global__ __launch_bounds__(TPB_SCAN) void fscan_kernel(
    const float* __restrict__ x, const __half* __restrict__ Wh,
    const int* __restrict__ src, const int* __restrict__ widx,
    const int* __restrict__ dst,
    float* __restrict__ partials, int E, int chunk)
{
    extern __shared__ float acc[];   // NPP floats = 80 KB
    int xcd = blockIdx.x % NXCD;
    int q   = blockIdx.x / NXCD;     // [0, 60)
    int p   = q % PARTS;
    int g   = q / PARTS;             // [0, GRP)
    int c   = g * NXCD + xcd;        // chunk id in [0, 48)

    float4* a4 = reinterpret_cast<float4*>(acc);
    for (int i = threadIdx.x; i < NPP / 4; i += TPB_SCAN)
        a4[i] = make_float4(0.f, 0.f, 0.f, 0.f);
    __syncthreads();

    int lo = c * chunk;              // chunk is a multiple of 4
    int hi = min(E, lo + chunk);     // E is a multiple of 4
    int base = p * NPP;

    const vint4* d4 = reinterpret_cast<const vint4*>(dst);
    const vint4* s4 = reinterpret_cast<const vint4*>(src);
    const vint4* w4 = reinterpret_cast<const vint4*>(widx);

    int glo = lo / 4, ghi = hi / 4;
    int gi = glo + threadIdx.x;

    // main batched loop: 2 int4-groups (8 edges) per thread per iteration,
    // all 6 stream loads issued before any use; then 16 predicated gathers;
    // then 8 LDS atomics.
    for (; gi + TPB_SCAN < ghi; gi += 2 * TPB_SCAN) {
        int gj = gi + TPB_SCAN;
        vint4 dA = d4[gi]; vint4 sA = s4[gi]; vint4 wA = w4[gi];
        vint4 dB = d4[gj]; vint4 sB = s4[gj]; vint4 wB = w4[gj];

        unsigned rA0 = (unsigned)(dA.x - base), rA1 = (unsigned)(dA.y - base);
        unsigned rA2 = (unsigned)(dA.z - base), rA3 = (unsigned)(dA.w - base);
        unsigned rB0 = (unsigned)(dB.x - base), rB1 = (unsigned)(dB.y - base);
        unsigned rB2 = (unsigned)(dB.z - base), rB3 = (unsigned)(dB.w - base);

        float mA0 = 0.f, mA1 = 0.f, mA2 = 0.f, mA3 = 0.f;
        float mB0 = 0.f, mB1 = 0.f, mB2 = 0.f, mB3 = 0.f;
        if (rA0 < NPP) mA0 = __half2float(Wh[wA.x]) * x[sA.x];
        if (rA1 < NPP) mA1 = __half2float(Wh[wA.y]) * x[sA.y];
        if (rA2 < NPP) mA2 = __half2float(Wh[wA.z]) * x[sA.z];
        if (rA3 < NPP) mA3 = __half2float(Wh[wA.w]) * x[sA.w];
        if (rB0 < NPP) mB0 = __half2float(Wh[wB.x]) * x[sB.x];
        if (rB1 < NPP) mB1 = __half2float(Wh[wB.y]) * x[sB.y];
        if (rB2 < NPP) mB2 = __half2float(Wh[wB.z]) * x[sB.z];
        if (rB3 < NPP) mB3 = __half2float(Wh[wB.w]) * x[sB.w];

        if (rA0 < NPP) atomicAdd(&acc[rA0], mA0);
        if (rA1 < NPP) atomicAdd(&acc[rA1], mA1);
        if (rA2 < NPP) atomicAdd(&acc[rA2], mA2);
        if (rA3 < NPP) atomicAdd(&acc[rA3], mA3);
        if (rB0 < NPP) atomicAdd(&acc[rB0], mB0);
        if (rB1 < NPP) atomicAdd(&acc[rB1], mB1);
        if (rB2 < NPP) atomicAdd(&acc[rB2], mB2);
        if (rB3 < NPP) atomicAdd(&acc[rB3], mB3);
    }
    // tail: single group
    for (; gi < ghi; gi += TPB_SCAN) {
        vint4 d = d4[gi]; vint4 s = s4[gi]; vint4 w = w4[gi];
        unsigned r0 = (unsigned)(d.x - base), r1 = (unsigned)(d.y - base);
        unsigned r2 = (unsigned)(d.z - base), r3 = (unsigned)(d.w - base);
        float m0 = 0.f, m1 = 0.f, m2 = 0.f, m3 = 0.f;
        if (r0 < NPP) m0 = __half2float(Wh[w.x]) * x[s.x];
        if (r1 < NPP) m1 = __half2float(Wh[w.y]) * x[s.y];
        if (r2 < NPP) m2 = __half2float(Wh[w.z]) * x[s.z];
        if (r3 < NPP) m3 = __half2float(Wh[w.w]) * x[s.w];
        if (r0 < NPP) atomicAdd(&acc[r0], m0);
        if (r1 < NPP) atomicAdd(&acc[r1], m1);
        if (r2 < NPP) atomicAdd(&acc[r2], m2);
        if (r3 < NPP) atomicAdd(&acc[r3], m3);
    }
    __syncthreads();

    vfloat4* out4 = reinterpret_cast<vfloat4*>(partials + (size_t)c * PADDED_N + base);
    const vfloat4* av4 = reinterpret_cast<const vfloat4*>(acc);
    for (int i = threadIdx.x; i < NPP / 4; i += TPB_SCAN)
        __builtin_nontemporal_store(av4[i], out4 + i);
}

// ---------------- Reduce: 48 slices + bias ----------------
__global__ __launch_bounds__(256) void reduce5_kernel(
    const float* __restrict__ partials, const float* __restrict__ bias,
    const int* __restrict__ label, float* __restrict__ y, int n)
{
    int i = blockIdx.x * 256 + threadIdx.x;
    if (i >= n) return;
    float s0 = bias[label[i]];
    float s1 = 0.f, s2 = 0.f, s3 = 0.f;
    const float* p = partials + i;
    #pragma unroll 1
    for (int c = 0; c < NCHUNKS; c += 4) {
        s0 += __builtin_nontemporal_load(p + (size_t)(c + 0) * PADDED_N);
        s1 += __builtin_nontemporal_load(p + (size_t)(c + 1) * PADDED_N);
        s2 += __builtin_nontemporal_load(p + (size_t)(c + 2) * PADDED_N);
        s3 += __builtin_nontemporal_load(p + (size_t)(c + 3) * PADDED_N);
    }
    y[i] = (s0 + s1) + (s2 + s3);
}

// ---------------- Fallback (direct atomics) if ws too small ----------------
__global__ __launch_bounds__(256) void bias_init_kernel(
    const float* __restrict__ Param_b, const int* __restrict__ node_label,
    float* __restrict__ y, int n_nodes)
{
    int i = blockIdx.x * blockDim.x + threadIdx.x;
    if (i < n_nodes) y[i] = Param_b[node_label[i]];
}

__global__ __launch_bounds__(256) void edge_scatter_kernel(
    const float* __restrict__ x, const float* __restrict__ Param_W,
    const int* __restrict__ src, const int* __restrict__ dst,
    const int* __restrict__ widx, float* __restrict__ y, int n_edges)
{
    int i = (blockIdx.x * blockDim.x + threadIdx.x) * 4;
    if (i + 3 < n_edges) {
        int4 s = *reinterpret_cast<const int4*>(src + i);
        int4 d = *reinterpret_cast<const int4*>(dst + i);
        int4 w = *reinterpret_cast<const int4*>(widx + i);
        unsafeAtomicAdd(&y[d.x], Param_W[w.x] * x[s.x]);
        unsafeAtomicAdd(&y[d.y], Param_W[w.y] * x[s.y]);
        unsafeAtomicAdd(&y[d.z], Param_W[w.z] * x[s.z]);
        unsafeAtomicAdd(&y[d.w], Param_W[w.w] * x[s.w]);
    } else {
        for (; i < n_edges; ++i)
            unsafeAtomicAdd(&y[dst[i]], Param_W[widx[i]] * x[src[i]]);
    }
}

extern "C" void kernel_launch(void* const* d_in, const int* in_sizes, int n_in,
                              void* d_out, int out_size, void* d_ws, size_t ws_size,
                              hipStream_t stream)
{
    const float* x          = (const float*)d_in[0];
    const float* Param_W    = (const float*)d_in[1];
    const float* Param_b    = (const float*)d_in[2];
    const int*   src        = (const int*)d_in[3];
    const int*   dst        = (const int*)d_in[4];
    const int*   weight_idx = (const int*)d_in[5];
    const int*   node_label = (const int*)d_in[6];
    float* y = (float*)d_out;

    int n_nodes = in_sizes[0];
    int W_n     = in_sizes[1];
    int E       = in_sizes[3];

    size_t wh_bytes       = ((size_t)W_n * sizeof(__half) + 255) & ~(size_t)255;  // 2MB
    size_t partials_elems = (size_t)NCHUNKS * PADDED_N;                            // 39.3 MB
    size_t need_bytes     = wh_bytes + partials_elems * sizeof(float);

    if (ws_size >= need_bytes) {
        __half* Wh       = (__half*)d_ws;
        float*  partials = (float*)((char*)d_ws + wh_bytes);

        // Phase 0: convert W to fp16 (ws re-poisoned every launch -> always rerun)
        int t0 = (W_n + 3) / 4;
        wconv_kernel<<<(t0 + 255) / 256, 256, 0, stream>>>(Param_W, Wh, W_n);

        // Fused gather + scan: 80 KB dynamic LDS, 480 blocks (2/CU, XCD-mapped)
        int chunk = (((E + NCHUNKS - 1) / NCHUNKS) + 3) & ~3;  // mult of 4
        fscan_kernel<<<PARTS * NCHUNKS, TPB_SCAN, NPP * sizeof(float), stream>>>(
            x, Wh, src, weight_idx, dst, partials, E, chunk);

        reduce5_kernel<<<(n_nodes + 255) / 256, 256, 0, stream>>>(
            partials, Param_b, node_label, y, n_nodes);
    } else {
        bias_init_kernel<<<(n_nodes + 255) / 256, 256, 0, stream>>>(
            Param_b, node_label, y, n_nodes);
        int t = (E + 3) / 4;
        edge_scatter_kernel<<<(t + 255) / 256, 256, 0, stream>>>(
            x, Param_W, src, dst, weight_idx, y, E);
    }
}

// Round 12
// 334.506 us; speedup vs baseline: 1.1050x; 1.1050x over previous
//
#include <hip/hip_runtime.h>
#include <hip/hip_fp16.h>

// ---------------- Constants ----------------
#define PARTS 5
#define NPP 40960                  // nodes per partition; 5*40960 = 204800 >= 200000
#define PADDED_N (PARTS * NPP)     // 204800
#define NXCD 8
#define GRP 6
#define NCHUNKS (NXCD * GRP)       // 48 chunks; scan grid = 240 blocks (1/CU)
#define TPB_SCAN 1024

typedef int   vint4   __attribute__((ext_vector_type(4)));
typedef float vfloat4 __attribute__((ext_vector_type(4)));

// ---------------- Phase 0: W f32 -> f16 (2MB table => L2-resident gathers) ----------------
__global__ __launch_bounds__(256) void wconv_kernel(
    const float* __restrict__ W, __half* __restrict__ Wh, int n)
{
    int i4 = (blockIdx.x * 256 + threadIdx.x) * 4;
    if (i4 + 3 < n) {
        vfloat4 w = *reinterpret_cast<const vfloat4*>(W + i4);
        __half2 h01 = __floats2half2_rn(w.x, w.y);
        __half2 h23 = __floats2half2_rn(w.z, w.w);
        *reinterpret_cast<__half2*>(Wh + i4)     = h01;
        *reinterpret_cast<__half2*>(Wh + i4 + 2) = h23;
    } else {
        for (; i4 < n; ++i4) Wh[i4] = __float2half(W[i4]);
    }
}

// ---------------- Phase A: msg[e] = Wh[widx[e]] * x[src[e]] ----------------
// NT loads on the once-read streams protect Wh(2MB)+x(0.8MB) L2 residency
// (r10 lesson). 8 edges/thread, all 16 gathers issued before any multiply
// (MLP; r6 structure). msg stays f32: keeps absmax where r10 passed, and
// the extra bytes ride L2/LLC in phase B.
__global__ __launch_bounds__(256) void msg_kernel(
    const float* __restrict__ x, const __half* __restrict__ Wh,
    const int* __restrict__ src, const int* __restrict__ widx,
    float* __restrict__ msg, int E)
{
    int i = (blockIdx.x * 256 + threadIdx.x) * 8;
    if (i + 7 < E) {
        vint4 s0 = __builtin_nontemporal_load(reinterpret_cast<const vint4*>(src + i));
        vint4 s1 = __builtin_nontemporal_load(reinterpret_cast<const vint4*>(src + i + 4));
        vint4 w0 = __builtin_nontemporal_load(reinterpret_cast<const vint4*>(widx + i));
        vint4 w1 = __builtin_nontemporal_load(reinterpret_cast<const vint4*>(widx + i + 4));

        float a0 = __half2float(Wh[w0.x]), a1 = __half2float(Wh[w0.y]);
        float a2 = __half2float(Wh[w0.z]), a3 = __half2float(Wh[w0.w]);
        float a4 = __half2float(Wh[w1.x]), a5 = __half2float(Wh[w1.y]);
        float a6 = __half2float(Wh[w1.z]), a7 = __half2float(Wh[w1.w]);
        float b0 = x[s0.x], b1 = x[s0.y], b2 = x[s0.z], b3 = x[s0.w];
        float b4 = x[s1.x], b5 = x[s1.y], b6 = x[s1.z], b7 = x[s1.w];

        vfloat4 m0, m1;
        m0.x = a0 * b0; m0.y = a1 * b1; m0.z = a2 * b2; m0.w = a3 * b3;
        m1.x = a4 * b4; m1.y = a5 * b5; m1.z = a6 * b6; m1.w = a7 * b7;
        // plain (temporal) stores: msg must stay in LLC for phase B (r7 lesson)
        *reinterpret_cast<vfloat4*>(msg + i)     = m0;
        *reinterpret_cast<vfloat4*>(msg + i + 4) = m1;
    } else {
        for (; i < E; ++i) msg[i] = __half2float(Wh[widx[i]]) * x[src[i]];
    }
}

// ---------------- Phase B: 5-partition broadcast scan over (dst, msg) ----------------
// XCD-aware mapping (r9): the 5 partition-readers of a chunk share blockIdx%8
// -> same XCD -> stream lines fetched beyond-L2 once, 4 L2 hits.
// Batch-2 inner loop for MLP (r11 structure, but only 2 streams now).
__global__ __launch_bounds__(TPB_SCAN) void scan5_kernel(
    const int* __restrict__ dst, const float* __restrict__ msg,
    float* __restrict__ partials, int E, int chunk)
{
    extern __shared__ float acc[];   // NPP floats = 160 KB
    int xcd = blockIdx.x % NXCD;
    int q   = blockIdx.x / NXCD;
    int p   = q % PARTS;
    int g   = q / PARTS;
    int c   = g * NXCD + xcd;        // chunk id in [0, 48)

    float4* a4 = reinterpret_cast<float4*>(acc);
    for (int i = threadIdx.x; i < NPP / 4; i += TPB_SCAN)
        a4[i] = make_float4(0.f, 0.f, 0.f, 0.f);
    __syncthreads();

    int lo = c * chunk;
    int hi = min(E, lo + chunk);
    int base = p * NPP;

    const vint4*   d4 = reinterpret_cast<const vint4*>(dst);
    const vfloat4* m4 = reinterpret_cast<const vfloat4*>(msg);

    int glo = lo / 4, ghi = hi / 4;
    int gi = glo + threadIdx.x;

    for (; gi + TPB_SCAN < ghi; gi += 2 * TPB_SCAN) {
        int gj = gi + TPB_SCAN;
        vint4   dA = d4[gi]; vfloat4 mA = m4[gi];
        vint4   dB = d4[gj]; vfloat4 mB = m4[gj];

        unsigned rA0 = (unsigned)(dA.x - base), rA1 = (unsigned)(dA.y - base);
        unsigned rA2 = (unsigned)(dA.z - base), rA3 = (unsigned)(dA.w - base);
        unsigned rB0 = (unsigned)(dB.x - base), rB1 = (unsigned)(dB.y - base);
        unsigned rB2 = (unsigned)(dB.z - base), rB3 = (unsigned)(dB.w - base);

        if (rA0 < NPP) atomicAdd(&acc[rA0], mA.x);
        if (rA1 < NPP) atomicAdd(&acc[rA1], mA.y);
        if (rA2 < NPP) atomicAdd(&acc[rA2], mA.z);
        if (rA3 < NPP) atomicAdd(&acc[rA3], mA.w);
        if (rB0 < NPP) atomicAdd(&acc[rB0], mB.x);
        if (rB1 < NPP) atomicAdd(&acc[rB1], mB.y);
        if (rB2 < NPP) atomicAdd(&acc[rB2], mB.z);
        if (rB3 < NPP) atomicAdd(&acc[rB3], mB.w);
    }
    for (; gi < ghi; gi += TPB_SCAN) {
        vint4 d = d4[gi]; vfloat4 m = m4[gi];
        unsigned r0 = (unsigned)(d.x - base), r1 = (unsigned)(d.y - base);
        unsigned r2 = (unsigned)(d.z - base), r3 = (unsigned)(d.w - base);
        if (r0 < NPP) atomicAdd(&acc[r0], m.x);
        if (r1 < NPP) atomicAdd(&acc[r1], m.y);
        if (r2 < NPP) atomicAdd(&acc[r2], m.z);
        if (r3 < NPP) atomicAdd(&acc[r3], m.w);
    }
    __syncthreads();

    vfloat4* out4 = reinterpret_cast<vfloat4*>(partials + (size_t)c * PADDED_N + base);
    const vfloat4* av4 = reinterpret_cast<const vfloat4*>(acc);
    for (int i = threadIdx.x; i < NPP / 4; i += TPB_SCAN)
        __builtin_nontemporal_store(av4[i], out4 + i);
}

// ---------------- Reduce: 48 slices + bias ----------------
__global__ __launch_bounds__(256) void reduce5_kernel(
    const float* __restrict__ partials, const float* __restrict__ bias,
    const int* __restrict__ label, float* __restrict__ y, int n)
{
    int i = blockIdx.x * 256 + threadIdx.x;
    if (i >= n) return;
    float s0 = bias[label[i]];
    float s1 = 0.f, s2 = 0.f, s3 = 0.f;
    const float* p = partials + i;
    #pragma unroll 1
    for (int c = 0; c < NCHUNKS; c += 4) {
        s0 += __builtin_nontemporal_load(p + (size_t)(c + 0) * PADDED_N);
        s1 += __builtin_nontemporal_load(p + (size_t)(c + 1) * PADDED_N);
        s2 += __builtin_nontemporal_load(p + (size_t)(c + 2) * PADDED_N);
        s3 += __builtin_nontemporal_load(p + (size_t)(c + 3) * PADDED_N);
    }
    y[i] = (s0 + s1) + (s2 + s3);
}

// ---------------- Fallback (direct atomics) if ws too small ----------------
__global__ __launch_bounds__(256) void bias_init_kernel(
    const float* __restrict__ Param_b, const int* __restrict__ node_label,
    float* __restrict__ y, int n_nodes)
{
    int i = blockIdx.x * blockDim.x + threadIdx.x;
    if (i < n_nodes) y[i] = Param_b[node_label[i]];
}

__global__ __launch_bounds__(256) void edge_scatter_kernel(
    const float* __restrict__ x, const float* __restrict__ Param_W,
    const int* __restrict__ src, const int* __restrict__ dst,
    const int* __restrict__ widx, float* __restrict__ y, int n_edges)
{
    int i = (blockIdx.x * blockDim.x + threadIdx.x) * 4;
    if (i + 3 < n_edges) {
        int4 s = *reinterpret_cast<const int4*>(src + i);
        int4 d = *reinterpret_cast<const int4*>(dst + i);
        int4 w = *reinterpret_cast<const int4*>(widx + i);
        unsafeAtomicAdd(&y[d.x], Param_W[w.x] * x[s.x]);
        unsafeAtomicAdd(&y[d.y], Param_W[w.y] * x[s.y]);
        unsafeAtomicAdd(&y[d.z], Param_W[w.z] * x[s.z]);
        unsafeAtomicAdd(&y[d.w], Param_W[w.w] * x[s.w]);
    } else {
        for (; i < n_edges; ++i)
            unsafeAtomicAdd(&y[dst[i]], Param_W[widx[i]] * x[src[i]]);
    }
}

extern "C" void kernel_launch(void* const* d_in, const int* in_sizes, int n_in,
                              void* d_out, int out_size, void* d_ws, size_t ws_size,
                              hipStream_t stream)
{
    const float* x          = (const float*)d_in[0];
    const float* Param_W    = (const float*)d_in[1];
    const float* Param_b    = (const float*)d_in[2];
    const int*   src        = (const int*)d_in[3];
    const int*   dst        = (const int*)d_in[4];
    const int*   weight_idx = (const int*)d_in[5];
    const int*   node_label = (const int*)d_in[6];
    float* y = (float*)d_out;

    int n_nodes = in_sizes[0];
    int W_n     = in_sizes[1];
    int E       = in_sizes[3];

    size_t wh_bytes       = ((size_t)W_n * sizeof(__half) + 255) & ~(size_t)255;  // 2MB
    size_t msg_bytes      = (size_t)E * sizeof(float);                            // 51.2MB
    size_t partials_elems = (size_t)NCHUNKS * PADDED_N;                           // 39.3MB
    size_t need_bytes     = wh_bytes + msg_bytes + partials_elems * sizeof(float);

    if (ws_size >= need_bytes) {
        __half* Wh       = (__half*)d_ws;
        float*  msg      = (float*)((char*)d_ws + wh_bytes);
        float*  partials = (float*)((char*)d_ws + wh_bytes + msg_bytes);

        // Phase 0: convert W to fp16 (ws re-poisoned every launch -> always rerun)
        int t0 = (W_n + 3) / 4;
        wconv_kernel<<<(t0 + 255) / 256, 256, 0, stream>>>(Param_W, Wh, W_n);

        // Phase A: gather-heavy msg computation, full MLP
        int tA = (E + 7) / 8;
        msg_kernel<<<(tA + 255) / 256, 256, 0, stream>>>(x, Wh, src, weight_idx, msg, E);

        // Phase B: stream-only broadcast scan, XCD-mapped, 160KB LDS, 1 block/CU
        int chunk = (((E + NCHUNKS - 1) / NCHUNKS) + 3) & ~3;  // mult of 4
        scan5_kernel<<<PARTS * NCHUNKS, TPB_SCAN, NPP * sizeof(float), stream>>>(
            dst, msg, partials, E, chunk);

        reduce5_kernel<<<(n_nodes + 255) / 256, 256, 0, stream>>>(
            partials, Param_b, node_label, y, n_nodes);
    } else {
        bias_init_kernel<<<(n_nodes + 255) / 256, 256, 0, stream>>>(
            Param_b, node_label, y, n_nodes);
        int t = (E + 3) / 4;
        edge_scatter_kernel<<<(t + 255) / 256, 256, 0, stream>>>(
            x, Param_W, src, dst, weight_idx, y, E);
    }
}

// Round 13
// 316.282 us; speedup vs baseline: 1.1687x; 1.0576x over previous
//
#include <hip/hip_runtime.h>
#include <hip/hip_fp16.h>

// ---------------- Fused pipelined broadcast-5 constants ----------------
#define PARTS 5
#define NPP 40960                  // nodes per partition; 5*40960 = 204800 >= 200000
#define PADDED_N (PARTS * NPP)     // 204800
#define NXCD 8
#define GRP 6
#define NCHUNKS (NXCD * GRP)       // 48 chunks; grid = 240 blocks (1/CU, XCD-mapped)
#define TPB_SCAN 1024

typedef int   vint4   __attribute__((ext_vector_type(4)));
typedef float vfloat4 __attribute__((ext_vector_type(4)));

// ---------------- Phase 0: W f32 -> f16 (2MB table => L2-resident gathers) ----------------
__global__ __launch_bounds__(256) void wconv_kernel(
    const float* __restrict__ W, __half* __restrict__ Wh, int n)
{
    int i4 = (blockIdx.x * 256 + threadIdx.x) * 4;
    if (i4 + 3 < n) {
        vfloat4 w = *reinterpret_cast<const vfloat4*>(W + i4);
        __half2 h01 = __floats2half2_rn(w.x, w.y);
        __half2 h23 = __floats2half2_rn(w.z, w.w);
        *reinterpret_cast<__half2*>(Wh + i4)     = h01;
        *reinterpret_cast<__half2*>(Wh + i4 + 2) = h23;
    } else {
        for (; i4 < n; ++i4) Wh[i4] = __float2half(W[i4]);
    }
}

// ---------------- Fused + software-pipelined gather/scan ----------------
// Accumulated lessons: XCD-aware mapping (r9: chunk's 5 readers share
// blockIdx%8 -> same XCD L2); fp16 W (r10: gathers L2-hit); temporal stream
// loads (r7: NT killed LLC reuse); PARTS=5 minimum passes (r11: passes cost
// issue). New (r13): rotated 2-stage pipeline — stage B's stream loads +
// predicated gathers are issued BEFORE stage A's LDS atomics consume
// register-resident values, so the vmcnt wait (at the A<-B rotation) lands
// after the atomics and the TA grinds gathers while the LDS pipe drains
// atomics, per wave, instead of serializing the two phases.
__global__ __launch_bounds__(TPB_SCAN) void fscan_kernel(
    const float* __restrict__ x, const __half* __restrict__ Wh,
    const int* __restrict__ src, const int* __restrict__ widx,
    const int* __restrict__ dst,
    float* __restrict__ partials, int E, int chunk)
{
    extern __shared__ float acc[];   // NPP floats = 160 KB
    int xcd = blockIdx.x % NXCD;
    int q   = blockIdx.x / NXCD;     // [0, 30)
    int p   = q % PARTS;
    int g   = q / PARTS;             // [0, GRP)
    int c   = g * NXCD + xcd;        // chunk id in [0, 48)

    float4* z4 = reinterpret_cast<float4*>(acc);
    for (int i = threadIdx.x; i < NPP / 4; i += TPB_SCAN)
        z4[i] = make_float4(0.f, 0.f, 0.f, 0.f);
    __syncthreads();

    int lo = c * chunk;              // chunk is a multiple of 4
    int hi = min(E, lo + chunk);     // E is a multiple of 4
    int base = p * NPP;

    const vint4* d4 = reinterpret_cast<const vint4*>(dst);
    const vint4* s4 = reinterpret_cast<const vint4*>(src);
    const vint4* w4 = reinterpret_cast<const vint4*>(widx);

    int ghi = hi / 4;
    int gi  = lo / 4 + threadIdx.x;

    // ---- stage A (prologue) ----
    unsigned rA0 = NPP, rA1 = NPP, rA2 = NPP, rA3 = NPP;
    float aA0 = 0.f, aA1 = 0.f, aA2 = 0.f, aA3 = 0.f;
    float bA0 = 0.f, bA1 = 0.f, bA2 = 0.f, bA3 = 0.f;
    bool haveA = (gi < ghi);
    if (haveA) {
        vint4 d = d4[gi], s = s4[gi], w = w4[gi];
        rA0 = (unsigned)(d.x - base); rA1 = (unsigned)(d.y - base);
        rA2 = (unsigned)(d.z - base); rA3 = (unsigned)(d.w - base);
        if (rA0 < NPP) { aA0 = __half2float(Wh[w.x]); bA0 = x[s.x]; }
        if (rA1 < NPP) { aA1 = __half2float(Wh[w.y]); bA1 = x[s.y]; }
        if (rA2 < NPP) { aA2 = __half2float(Wh[w.z]); bA2 = x[s.z]; }
        if (rA3 < NPP) { aA3 = __half2float(Wh[w.w]); bA3 = x[s.w]; }
    }

    while (haveA) {
        // ---- issue stage B (loads in flight across A's atomics) ----
        int gj = gi + TPB_SCAN;
        bool haveB = (gj < ghi);
        unsigned rB0 = NPP, rB1 = NPP, rB2 = NPP, rB3 = NPP;
        float aB0 = 0.f, aB1 = 0.f, aB2 = 0.f, aB3 = 0.f;
        float bB0 = 0.f, bB1 = 0.f, bB2 = 0.f, bB3 = 0.f;
        if (haveB) {
            vint4 d = d4[gj], s = s4[gj], w = w4[gj];
            rB0 = (unsigned)(d.x - base); rB1 = (unsigned)(d.y - base);
            rB2 = (unsigned)(d.z - base); rB3 = (unsigned)(d.w - base);
            if (rB0 < NPP) { aB0 = __half2float(Wh[w.x]); bB0 = x[s.x]; }
            if (rB1 < NPP) { aB1 = __half2float(Wh[w.y]); bB1 = x[s.y]; }
            if (rB2 < NPP) { aB2 = __half2float(Wh[w.z]); bB2 = x[s.z]; }
            if (rB3 < NPP) { aB3 = __half2float(Wh[w.w]); bB3 = x[s.w]; }
        }

        // ---- consume stage A (register-resident; no memory wait) ----
        if (rA0 < NPP) atomicAdd(&acc[rA0], aA0 * bA0);
        if (rA1 < NPP) atomicAdd(&acc[rA1], aA1 * bA1);
        if (rA2 < NPP) atomicAdd(&acc[rA2], aA2 * bA2);
        if (rA3 < NPP) atomicAdd(&acc[rA3], aA3 * bA3);

        // ---- rotate B -> A (vmcnt wait lands here, after the atomics) ----
        rA0 = rB0; rA1 = rB1; rA2 = rB2; rA3 = rB3;
        aA0 = aB0; aA1 = aB1; aA2 = aB2; aA3 = aB3;
        bA0 = bB0; bA1 = bB1; bA2 = bB2; bA3 = bB3;
        gi = gj; haveA = haveB;
    }
    __syncthreads();

    vfloat4* out4 = reinterpret_cast<vfloat4*>(partials + (size_t)c * PADDED_N + base);
    const vfloat4* av4 = reinterpret_cast<const vfloat4*>(acc);
    for (int i = threadIdx.x; i < NPP / 4; i += TPB_SCAN)
        __builtin_nontemporal_store(av4[i], out4 + i);
}

// ---------------- Reduce: 48 slices + bias ----------------
__global__ __launch_bounds__(256) void reduce5_kernel(
    const float* __restrict__ partials, const float* __restrict__ bias,
    const int* __restrict__ label, float* __restrict__ y, int n)
{
    int i = blockIdx.x * 256 + threadIdx.x;
    if (i >= n) return;
    float s0 = bias[label[i]];
    float s1 = 0.f, s2 = 0.f, s3 = 0.f;
    const float* p = partials + i;
    #pragma unroll 1
    for (int c = 0; c < NCHUNKS; c += 4) {
        s0 += __builtin_nontemporal_load(p + (size_t)(c + 0) * PADDED_N);
        s1 += __builtin_nontemporal_load(p + (size_t)(c + 1) * PADDED_N);
        s2 += __builtin_nontemporal_load(p + (size_t)(c + 2) * PADDED_N);
        s3 += __builtin_nontemporal_load(p + (size_t)(c + 3) * PADDED_N);
    }
    y[i] = (s0 + s1) + (s2 + s3);
}

// ---------------- Fallback (direct atomics) if ws too small ----------------
__global__ __launch_bounds__(256) void bias_init_kernel(
    const float* __restrict__ Param_b, const int* __restrict__ node_label,
    float* __restrict__ y, int n_nodes)
{
    int i = blockIdx.x * blockDim.x + threadIdx.x;
    if (i < n_nodes) y[i] = Param_b[node_label[i]];
}

__global__ __launch_bounds__(256) void edge_scatter_kernel(
    const float* __restrict__ x, const float* __restrict__ Param_W,
    const int* __restrict__ src, const int* __restrict__ dst,
    const int* __restrict__ widx, float* __restrict__ y, int n_edges)
{
    int i = (blockIdx.x * blockDim.x + threadIdx.x) * 4;
    if (i + 3 < n_edges) {
        int4 s = *reinterpret_cast<const int4*>(src + i);
        int4 d = *reinterpret_cast<const int4*>(dst + i);
        int4 w = *reinterpret_cast<const int4*>(widx + i);
        unsafeAtomicAdd(&y[d.x], Param_W[w.x] * x[s.x]);
        unsafeAtomicAdd(&y[d.y], Param_W[w.y] * x[s.y]);
        unsafeAtomicAdd(&y[d.z], Param_W[w.z] * x[s.z]);
        unsafeAtomicAdd(&y[d.w], Param_W[w.w] * x[s.w]);
    } else {
        for (; i < n_edges; ++i)
            unsafeAtomicAdd(&y[dst[i]], Param_W[widx[i]] * x[src[i]]);
    }
}

extern "C" void kernel_launch(void* const* d_in, const int* in_sizes, int n_in,
                              void* d_out, int out_size, void* d_ws, size_t ws_size,
                              hipStream_t stream)
{
    const float* x          = (const float*)d_in[0];
    const float* Param_W    = (const float*)d_in[1];
    const float* Param_b    = (const float*)d_in[2];
    const int*   src        = (const int*)d_in[3];
    const int*   dst        = (const int*)d_in[4];
    const int*   weight_idx = (const int*)d_in[5];
    const int*   node_label = (const int*)d_in[6];
    float* y = (float*)d_out;

    int n_nodes = in_sizes[0];
    int W_n     = in_sizes[1];
    int E       = in_sizes[3];

    size_t wh_bytes       = ((size_t)W_n * sizeof(__half) + 255) & ~(size_t)255;  // 2MB
    size_t partials_elems = (size_t)NCHUNKS * PADDED_N;                            // 39.3MB
    size_t need_bytes     = wh_bytes + partials_elems * sizeof(float);

    if (ws_size >= need_bytes) {
        __half* Wh       = (__half*)d_ws;
        float*  partials = (float*)((char*)d_ws + wh_bytes);

        // Phase 0: convert W to fp16 (ws re-poisoned every launch -> always rerun)
        int t0 = (W_n + 3) / 4;
        wconv_kernel<<<(t0 + 255) / 256, 256, 0, stream>>>(Param_W, Wh, W_n);

        // Fused pipelined gather+scan: 160 KB dynamic LDS, 240 blocks (1/CU)
        int chunk = (((E + NCHUNKS - 1) / NCHUNKS) + 3) & ~3;  // mult of 4
        fscan_kernel<<<PARTS * NCHUNKS, TPB_SCAN, NPP * sizeof(float), stream>>>(
            x, Wh, src, weight_idx, dst, partials, E, chunk);

        reduce5_kernel<<<(n_nodes + 255) / 256, 256, 0, stream>>>(
            partials, Param_b, node_label, y, n_nodes);
    } else {
        bias_init_kernel<<<(n_nodes + 255) / 256, 256, 0, stream>>>(
            Param_b, node_label, y, n_nodes);
        int t = (E + 3) / 4;
        edge_scatter_kernel<<<(t + 255) / 256, 256, 0, stream>>>(
            x, Param_W, src, dst, weight_idx, y, E);
    }
}